// Round 13
// baseline (384.805 us; speedup 1.0000x reference)
//
#include <hip/hip_runtime.h>
#include <math.h>

// Problem constants
#define NB 16
#define NC 64
#define NL 4096            // 64*64
#define EPSF 1e-5f
#define LOG_EPSF -11.512925464970229f   // log(1e-5)

// d_ws layout (float offsets)
#define WS_W2T   0         // [64c][64o]  w2[o][c]^2 / r2[o]
#define WS_RHO   4096      // [64]        r2[o] / s22
#define WS_CLS   4160      // smag(+EPS)[64][9] then tang[64][9], contiguous 1152
#define WS_WQ2   5312      // [64c][9k][2] = (w1^2/rowsum, w1^2/globalsum) pairs

// ---------------- prep: ALL weight math -> d_ws ----------------
__global__ __launch_bounds__(256) void prep_kernel(
    const float* __restrict__ wm, const float* __restrict__ wa,
    const float* __restrict__ w1, const float* __restrict__ w2,
    float* __restrict__ ws)
{
    __shared__ float r2s[64];
    __shared__ float red[3][4];
    const int tid  = threadIdx.x;
    const int lane = tid & 63;
    const int wv   = tid >> 6;

    if (tid < 64) {
        float s = 0.f;
        for (int c = 0; c < 64; ++c) { float v = w2[tid * 64 + c]; s = fmaf(v, v, s); }
        r2s[tid] = s;
    }
    float p0 = 0.f, p1 = 0.f, p2 = 0.f;
    {
        float v;
        v = wm[tid]; p0 += v * v;  v = wm[tid + 256]; p0 += v * v;
        v = wa[tid]; p1 += v * v;  v = wa[tid + 256]; p1 += v * v;
        v = w1[tid]; p2 += v * v;  v = w1[tid + 256]; p2 += v * v;
        if (tid < 64) {
            v = wm[tid + 512]; p0 += v * v;
            v = wa[tid + 512]; p1 += v * v;
            v = w1[tid + 512]; p2 += v * v;
        }
    }
    #pragma unroll
    for (int s = 32; s; s >>= 1) {
        p0 += __shfl_down(p0, s); p1 += __shfl_down(p1, s); p2 += __shfl_down(p2, s);
    }
    if (lane == 0) { red[0][wv] = p0; red[1][wv] = p1; red[2][wv] = p2; }
    __syncthreads();
    const float s_wm2 = red[0][0] + red[0][1] + red[0][2] + red[0][3];
    const float s_wa2 = red[1][0] + red[1][1] + red[1][2] + red[1][3];
    const float s_w12 = red[2][0] + red[2][1] + red[2][2] + red[2][3];

    // this block's w2t slice: channels c0..c0+3
    const int c0 = blockIdx.x * 4;
    {
        int c = c0 + (tid >> 6), o = tid & 63;
        float v = w2[o * 64 + c];
        ws[WS_W2T + c * 64 + o] = v * v / r2s[o];
    }

    if (blockIdx.x == 0) {
        if (tid < 64) {
            float s22 = 0.f;
            #pragma unroll
            for (int o = 0; o < 64; ++o) s22 += r2s[o];
            ws[WS_RHO + tid] = r2s[tid] / s22;

            const int c = tid;
            float nm[9], na[9];
            const float inv_m = 1.f / s_wm2, inv_a = 1.f / s_wa2;
            #pragma unroll
            for (int k = 0; k < 9; ++k) {
                float v = wm[c * 9 + k];
                nm[k] = v * v * inv_m;
                na[k] = wa[c * 9 + k] * inv_a;
            }
            #pragma unroll
            for (int ci_ = 0; ci_ < 3; ++ci_) {
                #pragma unroll
                for (int cj = 0; cj < 3; ++cj) {
                    float sm = 0.f, sa = 0.f;
                    #pragma unroll
                    for (int ki = 0; ki < 3; ++ki) {
                        bool vi = (ci_ == 0) ? (ki < 2) : ((ci_ == 2) ? (ki > 0) : true);
                        if (!vi) continue;
                        #pragma unroll
                        for (int kj = 0; kj < 3; ++kj) {
                            bool vj = (cj == 0) ? (kj < 2) : ((cj == 2) ? (kj > 0) : true);
                            if (!vj) continue;
                            sm += nm[ki * 3 + kj];
                            sa += na[ki * 3 + kj];
                        }
                    }
                    // store smag WITH +EPS folded in (stage computes log(n*x + S))
                    ws[WS_CLS + c * 9 + ci_ * 3 + cj] = sm + EPSF;
                    ws[WS_CLS + 576 + c * 9 + ci_ * 3 + cj] = sa;
                }
            }
            float q[9]; float r1c = 0.f;
            #pragma unroll
            for (int k = 0; k < 9; ++k) { float v = w1[c * 9 + k]; q[k] = v * v; r1c += q[k]; }
            const float inv_r = 1.f / r1c, inv_s = 1.f / s_w12;
            #pragma unroll
            for (int k = 0; k < 9; ++k) {
                ws[WS_WQ2 + c * 18 + 2 * k]     = q[k] * inv_r;
                ws[WS_WQ2 + c * 18 + 2 * k + 1] = q[k] * inv_s;
            }
        }
    }
}

// ---------------- fused main: barrier-free channel loop ----------------
// Block = (b, output row iy), 256 threads = 4 waves.
// lane = pixel column l. Wave wv owns channels [wv*16, wv*16+16).
// Per channel: 6 coalesced scalar loads -> stage in regs -> conv via 2 shfl
// (t/u/v column-sum trick) -> 128 reg-FMA matmul with SGPR weights.
// NO LDS, NO barriers in the loop. Cross-wave combine: ds_add_f32 once.
__global__ __launch_bounds__(256, 2) void fused_kernel(
    const float* __restrict__ x_mag, const float* __restrict__ x_ang,
    const float* __restrict__ ws, float* __restrict__ out)
{
    __shared__ float buf[2][64][64];     // 32 KB partial-sum buffer

    const int tid  = threadIdx.x;
    const int lane = tid & 63;
    const int wv   = tid >> 6;

    // zero buf (8 f4 per thread), fence before atomics
    {
        float4 z4; z4.x = z4.y = z4.z = z4.w = 0.f;
        #pragma unroll
        for (int k = 0; k < 8; ++k) ((float4*)buf)[tid + k * 256] = z4;
    }
    __syncthreads();

    // XCD swizzle: 1024 % 8 == 0 -> bijective
    const int bid = (blockIdx.x & 7) * 128 + (blockIdx.x >> 3);
    const int b  = bid >> 6;
    const int iy = bid & 63;

    // row classes (wave-uniform)
    const int ir0 = iy - 1, ir2 = iy + 1;
    const bool ok0 = (ir0 >= 0), ok2 = (ir2 < 64);
    const int ci0 = (ir0 == 0) ? 0 : 1;               // (invalid row unused)
    const int ci1 = (iy == 0) ? 0 : ((iy == 63) ? 2 : 1);
    const int ci2 = (ir2 == 63) ? 2 : 1;
    const int ro0 = ok0 ? ir0 * 64 : 0;
    const int ro1 = iy * 64;
    const int ro2 = ok2 ? ir2 * 64 : 0;

    const bool e0  = (lane == 0);
    const bool e63 = (lane == 63);
    const bool edge = e0 | e63;

    const int cbase = wv * 16;
    const float* xmb = x_mag + ((size_t)(b * NC + cbase) * NL) + lane;
    const float* xab = x_ang + ((size_t)(b * NC + cbase) * NL) + lane;

    float pm[3][3], pa[3][3];            // 3-deep ping-pong prefetch
    auto loadCh = [&](int t, int s) {
        const int off = t * NL;
        pm[s][0] = xmb[off + ro0]; pm[s][1] = xmb[off + ro1]; pm[s][2] = xmb[off + ro2];
        pa[s][0] = xab[off + ro0]; pa[s][1] = xab[off + ro1]; pa[s][2] = xab[off + ro2];
    };

    float accm[64], acca[64];
    #pragma unroll
    for (int o = 0; o < 64; ++o) { accm[o] = 0.f; acca[o] = 0.f; }

    loadCh(0, 0);
    loadCh(1, 1);

    #pragma unroll
    for (int t = 0; t < 16; ++t) {
        if (t + 2 < 16) loadCh(t + 2, (t + 2) % 3);
        const int s = t % 3;

        const int cu = __builtin_amdgcn_readfirstlane(cbase + t);
        const float* clm = ws + WS_CLS + cu * 9;          // smag(+eps) row
        const float* cla = ws + WS_CLS + 576 + cu * 9;    // tang row
        const float* qw  = ws + WS_WQ2 + cu * 18;
        const float* wrow = ws + WS_W2T + (cu << 6);

        float qm[9], qa[9];
        #pragma unroll
        for (int k = 0; k < 9; ++k) { qm[k] = qw[2 * k]; qa[k] = qw[2 * k + 1]; }

        // ---- stage (registers) ----
        float lm0, lm1, lm2, fa0, fa1, fa2;
        {
            // row 1 (always valid)
            {
                float Sc = clm[ci1 * 3 + 1], Tc = cla[ci1 * 3 + 1];
                float S = e0 ? clm[ci1 * 3] : (e63 ? clm[ci1 * 3 + 2] : Sc);
                float T = e0 ? cla[ci1 * 3] : (e63 ? cla[ci1 * 3 + 2] : Tc);
                float ni = (ci1 == 1) ? 3.f : 2.f;
                float n = edge ? 2.f * ni : 3.f * ni;
                lm1 = __logf(fmaf(n, pm[s][1], S));
                fa1 = pa[s][1] * T;
            }
            if (ok0) {
                float Sc = clm[ci0 * 3 + 1], Tc = cla[ci0 * 3 + 1];
                float S = e0 ? clm[ci0 * 3] : (e63 ? clm[ci0 * 3 + 2] : Sc);
                float T = e0 ? cla[ci0 * 3] : (e63 ? cla[ci0 * 3 + 2] : Tc);
                float ni = (ci0 == 1) ? 3.f : 2.f;
                float n = edge ? 2.f * ni : 3.f * ni;
                lm0 = __logf(fmaf(n, pm[s][0], S));
                fa0 = pa[s][0] * T;
            } else { lm0 = LOG_EPSF; fa0 = 0.f; }
            if (ok2) {
                float Sc = clm[ci2 * 3 + 1], Tc = cla[ci2 * 3 + 1];
                float S = e0 ? clm[ci2 * 3] : (e63 ? clm[ci2 * 3 + 2] : Sc);
                float T = e0 ? cla[ci2 * 3] : (e63 ? cla[ci2 * 3 + 2] : Tc);
                float ni = (ci2 == 1) ? 3.f : 2.f;
                float n = edge ? 2.f * ni : 3.f * ni;
                lm2 = __logf(fmaf(n, pm[s][2], S));
                fa2 = pa[s][2] * T;
            } else { lm2 = LOG_EPSF; fa2 = 0.f; }
        }

        // ---- conv via column-sum + shfl ----
        float m1, a1;
        {
            float tm = qm[0] * lm0; tm = fmaf(qm[3], lm1, tm); tm = fmaf(qm[6], lm2, tm);
            float um = qm[1] * lm0; um = fmaf(qm[4], lm1, um); um = fmaf(qm[7], lm2, um);
            float vm = qm[2] * lm0; vm = fmaf(qm[5], lm1, vm); vm = fmaf(qm[8], lm2, vm);
            float sentL = LOG_EPSF * (qm[0] + qm[3] + qm[6]);
            float sentR = LOG_EPSF * (qm[2] + qm[5] + qm[8]);
            float tmL = __shfl_up(tm, 1);
            float vmR = __shfl_down(vm, 1);
            tmL = e0  ? sentL : tmL;
            vmR = e63 ? sentR : vmR;
            m1 = tmL + um + vmR;

            float ta = qa[0] * fa0; ta = fmaf(qa[3], fa1, ta); ta = fmaf(qa[6], fa2, ta);
            float ua = qa[1] * fa0; ua = fmaf(qa[4], fa1, ua); ua = fmaf(qa[7], fa2, ua);
            float va = qa[2] * fa0; va = fmaf(qa[5], fa1, va); va = fmaf(qa[8], fa2, va);
            float taL = __shfl_up(ta, 1);
            float vaR = __shfl_down(va, 1);
            taL = e0  ? 0.f : taL;
            vaR = e63 ? 0.f : vaR;
            a1 = taL + ua + vaR;
        }

        // ---- matmul: 128 FMA, SGPR weights x lane-local data ----
        #pragma unroll
        for (int ob = 0; ob < 4; ++ob) {
            #pragma unroll
            for (int k = 0; k < 16; ++k) {
                float w = wrow[ob * 16 + k];
                accm[ob * 16 + k] = fmaf(w, m1, accm[ob * 16 + k]);
                acca[ob * 16 + k] = fmaf(w, a1, acca[ob * 16 + k]);
            }
        }
    }

    // ---- cross-wave combine: LDS float atomics (conflict-free addressing) ----
    #pragma unroll
    for (int o = 0; o < 64; ++o) {
        atomicAdd(&buf[0][o][lane], accm[o]);
        atomicAdd(&buf[1][o][lane], acca[o]);
    }
    __syncthreads();

    // ---- epilogue: wave wv finalizes o in [wv*16, wv*16+16) ----
    #pragma unroll
    for (int k = 0; k < 16; ++k) {
        const int o = wv * 16 + k;
        const float rho_o = ws[WS_RHO + o];      // wave-uniform -> s_load
        float sm = buf[0][o][lane];
        float sa = buf[1][o][lane] * rho_o;
        float mg = __expf(sm);
        float oc = mg * __cosf(sa);
        float os = mg * __sinf(sa);
        size_t gi = ((size_t)(b * 2) * NC + o) * NL + (size_t)iy * 64 + lane;
        out[gi] = oc;
        out[gi + (size_t)NC * NL] = os;
    }
}

extern "C" void kernel_launch(void* const* d_in, const int* in_sizes, int n_in,
                              void* d_out, int out_size, void* d_ws, size_t ws_size,
                              hipStream_t stream) {
    const float* x_mag = (const float*)d_in[0];
    const float* x_ang = (const float*)d_in[1];
    const float* w_mag = (const float*)d_in[2];
    const float* w_ang = (const float*)d_in[3];
    const float* w1    = (const float*)d_in[4];
    const float* w2    = (const float*)d_in[5];
    float* out = (float*)d_out;
    float* ws  = (float*)d_ws;

    prep_kernel<<<16, 256, 0, stream>>>(w_mag, w_ang, w1, w2, ws);
    fused_kernel<<<NB * 64, 256, 0, stream>>>(x_mag, x_ang, ws, out);
}

// Round 14
// 41.287 us; speedup vs baseline: 9.3201x; 9.3201x over previous
//
#include <hip/hip_runtime.h>
#include <math.h>

// Problem constants
#define NB 16
#define NC 64
#define NL 4096            // 64*64
#define EPSF 1e-5f
#define LOG_EPSF -11.512925464970229f   // log(1e-5)
#define CC 4               // channels per chunk (= waves per block)
#define NCHUNK 16

// d_ws layout (float offsets)
#define WS_W2T   0         // [64c][64o]  w2[o][c]^2 / r2[o]
#define WS_RHO   4096      // [64]        r2[o] / s22
#define WS_CLS   4160      // smag[64][9] then tang[64][9], contiguous 1152
#define WS_WQ2   5312      // [64c][9k][2] = (w1^2/rowsum, w1^2/globalsum) pairs

typedef float f32x2 __attribute__((ext_vector_type(2)));

// ACC = float4[4] (4 o's), MV = data l-vector, W = 4 o-weights
#define FMA16(ACC, MV, W) \
  (ACC)[0].x = fmaf((MV).x,(W).x,(ACC)[0].x); (ACC)[0].y = fmaf((MV).y,(W).x,(ACC)[0].y); \
  (ACC)[0].z = fmaf((MV).z,(W).x,(ACC)[0].z); (ACC)[0].w = fmaf((MV).w,(W).x,(ACC)[0].w); \
  (ACC)[1].x = fmaf((MV).x,(W).y,(ACC)[1].x); (ACC)[1].y = fmaf((MV).y,(W).y,(ACC)[1].y); \
  (ACC)[1].z = fmaf((MV).z,(W).y,(ACC)[1].z); (ACC)[1].w = fmaf((MV).w,(W).y,(ACC)[1].w); \
  (ACC)[2].x = fmaf((MV).x,(W).z,(ACC)[2].x); (ACC)[2].y = fmaf((MV).y,(W).z,(ACC)[2].y); \
  (ACC)[2].z = fmaf((MV).z,(W).z,(ACC)[2].z); (ACC)[2].w = fmaf((MV).w,(W).z,(ACC)[2].w); \
  (ACC)[3].x = fmaf((MV).x,(W).w,(ACC)[3].x); (ACC)[3].y = fmaf((MV).y,(W).w,(ACC)[3].y); \
  (ACC)[3].z = fmaf((MV).z,(W).w,(ACC)[3].z); (ACC)[3].w = fmaf((MV).w,(W).w,(ACC)[3].w);

// ---------------- prep: ALL weight math -> d_ws ----------------
__global__ __launch_bounds__(256) void prep_kernel(
    const float* __restrict__ wm, const float* __restrict__ wa,
    const float* __restrict__ w1, const float* __restrict__ w2,
    float* __restrict__ ws)
{
    __shared__ float r2s[64];
    __shared__ float red[3][4];
    const int tid  = threadIdx.x;
    const int lane = tid & 63;
    const int wv   = tid >> 6;

    if (tid < 64) {
        float s = 0.f;
        for (int c = 0; c < 64; ++c) { float v = w2[tid * 64 + c]; s = fmaf(v, v, s); }
        r2s[tid] = s;
    }
    float p0 = 0.f, p1 = 0.f, p2 = 0.f;
    {
        float v;
        v = wm[tid]; p0 += v * v;  v = wm[tid + 256]; p0 += v * v;
        v = wa[tid]; p1 += v * v;  v = wa[tid + 256]; p1 += v * v;
        v = w1[tid]; p2 += v * v;  v = w1[tid + 256]; p2 += v * v;
        if (tid < 64) {
            v = wm[tid + 512]; p0 += v * v;
            v = wa[tid + 512]; p1 += v * v;
            v = w1[tid + 512]; p2 += v * v;
        }
    }
    #pragma unroll
    for (int s = 32; s; s >>= 1) {
        p0 += __shfl_down(p0, s); p1 += __shfl_down(p1, s); p2 += __shfl_down(p2, s);
    }
    if (lane == 0) { red[0][wv] = p0; red[1][wv] = p1; red[2][wv] = p2; }
    __syncthreads();
    const float s_wm2 = red[0][0] + red[0][1] + red[0][2] + red[0][3];
    const float s_wa2 = red[1][0] + red[1][1] + red[1][2] + red[1][3];
    const float s_w12 = red[2][0] + red[2][1] + red[2][2] + red[2][3];

    // this block's w2t slice: channels c0..c0+3
    const int c0 = blockIdx.x * 4;
    {
        int c = c0 + (tid >> 6), o = tid & 63;
        float v = w2[o * 64 + c];
        ws[WS_W2T + c * 64 + o] = v * v / r2s[o];
    }

    if (blockIdx.x == 0) {
        if (tid < 64) {
            float s22 = 0.f;
            #pragma unroll
            for (int o = 0; o < 64; ++o) s22 += r2s[o];
            ws[WS_RHO + tid] = r2s[tid] / s22;

            const int c = tid;
            float nm[9], na[9];
            const float inv_m = 1.f / s_wm2, inv_a = 1.f / s_wa2;
            #pragma unroll
            for (int k = 0; k < 9; ++k) {
                float v = wm[c * 9 + k];
                nm[k] = v * v * inv_m;
                na[k] = wa[c * 9 + k] * inv_a;
            }
            #pragma unroll
            for (int ci_ = 0; ci_ < 3; ++ci_) {
                #pragma unroll
                for (int cj = 0; cj < 3; ++cj) {
                    float sm = 0.f, sa = 0.f;
                    #pragma unroll
                    for (int ki = 0; ki < 3; ++ki) {
                        bool vi = (ci_ == 0) ? (ki < 2) : ((ci_ == 2) ? (ki > 0) : true);
                        if (!vi) continue;
                        #pragma unroll
                        for (int kj = 0; kj < 3; ++kj) {
                            bool vj = (cj == 0) ? (kj < 2) : ((cj == 2) ? (kj > 0) : true);
                            if (!vj) continue;
                            sm += nm[ki * 3 + kj];
                            sa += na[ki * 3 + kj];
                        }
                    }
                    ws[WS_CLS + c * 9 + ci_ * 3 + cj] = sm;
                    ws[WS_CLS + 576 + c * 9 + ci_ * 3 + cj] = sa;
                }
            }
            float q[9]; float r1c = 0.f;
            #pragma unroll
            for (int k = 0; k < 9; ++k) { float v = w1[c * 9 + k]; q[k] = v * v; r1c += q[k]; }
            const float inv_r = 1.f / r1c, inv_s = 1.f / s_w12;
            #pragma unroll
            for (int k = 0; k < 9; ++k) {
                ws[WS_WQ2 + c * 18 + 2 * k]     = q[k] * inv_r;
                ws[WS_WQ2 + c * 18 + 2 * k + 1] = q[k] * inv_s;
            }
        }
    }
}

// ---------------- fused main: 1 output row per block ----------------
__global__ __launch_bounds__(256, 4) void fused_kernel(
    const float* __restrict__ x_mag, const float* __restrict__ x_ang,
    const float* __restrict__ ws, float* __restrict__ out)
{
    // LDS ~15.6 KB -> 4 blocks/CU (grid 1024)
    __shared__ __align__(16) float lf2[CC][3][144];     // packed (logmag, ang): pixel j at floats 8+2j (wave-private slot)
    __shared__ __align__(16) float m1r[2][CC][64];      // conv out (mag), parity dbuf
    __shared__ __align__(16) float a1r[2][CC][64];      // conv out (ang)
    __shared__ __align__(16) float cls_s[1152];         // smag[0..575], tang[576..1151]

    const int tid  = threadIdx.x;
    const int lane = tid & 63;
    const int wv   = tid >> 6;           // 0..3

    // XCD swizzle: 1024 % 8 == 0 -> bijective; 128 consecutive bids (2 images) per XCD
    const int bid = (blockIdx.x & 7) * 128 + (blockIdx.x >> 3);
    const int b  = bid >> 6;
    const int iy = bid & 63;             // block owns output row iy

    // ---- stage mapping: wave wv stages channel (ch*CC+wv); lane -> (sr, j4) ----
    const int sr = lane >> 4;            // staged row 0..2 -> image row iy-1+sr (sr==3 idle)
    const int j4 = lane & 15;
    const bool act = (sr < 3);
    const int ir = iy - 1 + sr;
    const bool ok = act && ((unsigned)ir < 64u);
    const int irc = ok ? ir : 0;
    const int ci = (ir == 0) ? 0 : ((ir == 63) ? 2 : 1);
    const int kL = ci * 3 + 0, kC = ci * 3 + 1, kR = ci * 3 + 2;
    const float ni = (ci == 1) ? 3.f : 2.f;
    const float nCt = 3.f * ni;
    const float n0 = (j4 == 0)  ? 2.f * ni : nCt;
    const float n3 = (j4 == 15) ? 2.f * ni : nCt;

    const float* spm = x_mag + ((size_t)(b * NC + wv) * NL + irc * 64 + j4 * 4);
    const float* spa = x_ang + ((size_t)(b * NC + wv) * NL + irc * 64 + j4 * 4);

    // chunk-0 prefetch in flight across init
    float4 pfm, pfa;
    if (act) { pfm = *(const float4*)spm; pfa = *(const float4*)spa; }

    // ---- matmul mapping: tid = o16(b7-4) | l16(b3-0); 4o x 4l x 2 sides ----
    const int o0 = (tid >> 4) * 4;
    const int l0 = (tid & 15) * 4;
    const float* w2t_g = ws + WS_W2T;

    // ---------- init: class tables -> LDS; hoisted sentinels ----------
    for (int t = tid; t < 288; t += 256)
        ((float4*)cls_s)[t] = ((const float4*)(ws + WS_CLS))[t];

    if (act) {
        if (j4 == 0)  { lf2[wv][sr][6]   = LOG_EPSF; lf2[wv][sr][7]   = 0.f; }
        if (j4 == 15) { lf2[wv][sr][136] = LOG_EPSF; lf2[wv][sr][137] = 0.f; }
        if (!ok) {
            float4 s4; s4.x = LOG_EPSF; s4.y = 0.f; s4.z = LOG_EPSF; s4.w = 0.f;
            *(float4*)&lf2[wv][sr][8 + 8 * j4]  = s4;
            *(float4*)&lf2[wv][sr][12 + 8 * j4] = s4;
        }
    }
    __syncthreads();

    // ---------- main channel loop ----------
    float4 accm[4], acca[4];             // 4 o's x 4 l's, both sides
    #pragma unroll
    for (int oi = 0; oi < 4; ++oi) {
        accm[oi].x = accm[oi].y = accm[oi].z = accm[oi].w = 0.f;
        acca[oi].x = acca[oi].y = acca[oi].z = acca[oi].w = 0.f;
    }

    auto do_matmul = [&](int chm, int pp) {
        const int c0 = chm * CC;
        #pragma unroll
        for (int cc = 0; cc < CC; ++cc) {
            const float* wg = w2t_g + (size_t)(c0 + cc) * 64 + o0;
            float4 w_ = *(const float4*)wg;          // VMEM (L1-resident 16KB table)
            float4 mv = *(const float4*)&m1r[pp][cc][l0];
            float4 av = *(const float4*)&a1r[pp][cc][l0];
            FMA16(accm, mv, w_);
            FMA16(acca, av, w_);         // ang uses same weights; *rho[o] in epilogue
        }
    };

    #pragma unroll 2
    for (int ch = 0; ch < NCHUNK; ++ch) {
        const int p = ch & 1;
        const int cg = ch * CC + wv;

        // ---- conv weights: wave-uniform s_loads (pre-normalized pairs) ----
        const int cgu = __builtin_amdgcn_readfirstlane(cg);
        const f32x2* qp = (const f32x2*)(ws + WS_WQ2 + cgu * 18);
        f32x2 q2[9];
        #pragma unroll
        for (int k = 0; k < 9; ++k) q2[k] = qp[k];

        // ---- matmul(ch-1) FIRST: its LDS data is ready after the barrier;
        //      this chunk's prefetch (issued last iter, still in flight) lands meanwhile ----
        if (ch > 0) do_matmul(ch - 1, p ^ 1);

        // ---- stage(ch): wave-local, packed (m,a) ----
        if (ok) {
            float sC = cls_s[cg * 9 + kC],       tC = cls_s[576 + cg * 9 + kC];
            float s0 = (j4 == 0)  ? cls_s[cg * 9 + kL] : sC;
            float s3 = (j4 == 15) ? cls_s[cg * 9 + kR] : sC;
            float t0 = (j4 == 0)  ? cls_s[576 + cg * 9 + kL] : tC;
            float t3 = (j4 == 15) ? cls_s[576 + cg * 9 + kR] : tC;
            float4 v0, v1;
            v0.x = __logf(fmaf(n0,  pfm.x, s0) + EPSF);
            v0.y = pfa.x * t0;
            v0.z = __logf(fmaf(nCt, pfm.y, sC) + EPSF);
            v0.w = pfa.y * tC;
            v1.x = __logf(fmaf(nCt, pfm.z, sC) + EPSF);
            v1.y = pfa.z * tC;
            v1.z = __logf(fmaf(n3,  pfm.w, s3) + EPSF);
            v1.w = pfa.w * t3;
            *(float4*)&lf2[wv][sr][8 + 8 * j4]  = v0;
            *(float4*)&lf2[wv][sr][12 + 8 * j4] = v1;
        }

        // ---- prefetch next chunk: stays IN FLIGHT across the barrier below ----
        if (act && (ch + 1 < NCHUNK)) {
            pfm = *(const float4*)(spm + (size_t)(ch + 1) * CC * NL);
            pfa = *(const float4*)(spa + (size_t)(ch + 1) * CC * NL);
        }

        // ---- conv(ch): 9 packed b64 reads + 9 pk-fma, pre-normalized weights ----
        {
            f32x2 a0; a0.x = 0.f; a0.y = 0.f;
            #pragma unroll
            for (int r_ = 0; r_ < 3; ++r_) {
                const float* rp = &lf2[wv][r_][0];
                f32x2 v0 = *(const f32x2*)(rp + 2 * lane + 6);
                f32x2 v1 = *(const f32x2*)(rp + 2 * lane + 8);
                f32x2 v2 = *(const f32x2*)(rp + 2 * lane + 10);
                a0 = __builtin_elementwise_fma(q2[r_ * 3 + 0], v0, a0);
                a0 = __builtin_elementwise_fma(q2[r_ * 3 + 1], v1, a0);
                a0 = __builtin_elementwise_fma(q2[r_ * 3 + 2], v2, a0);
            }
            m1r[p][wv][lane] = a0.x;
            a1r[p][wv][lane] = a0.y;
        }

        // ---- T4 barrier: fence LDS only (lgkmcnt), leave global prefetch
        //      loads IN FLIGHT (no vmcnt drain — __syncthreads would drain). ----
        __builtin_amdgcn_sched_barrier(0);
        asm volatile("s_waitcnt lgkmcnt(0)" ::: "memory");
        __builtin_amdgcn_s_barrier();
        __builtin_amdgcn_sched_barrier(0);
    }
    do_matmul(NCHUNK - 1, 1);

    // ---------- epilogue ----------
    {
        const float4 rh = *(const float4*)(ws + WS_RHO + o0);
        acca[0].x *= rh.x; acca[0].y *= rh.x; acca[0].z *= rh.x; acca[0].w *= rh.x;
        acca[1].x *= rh.y; acca[1].y *= rh.y; acca[1].z *= rh.y; acca[1].w *= rh.y;
        acca[2].x *= rh.z; acca[2].y *= rh.z; acca[2].z *= rh.z; acca[2].w *= rh.z;
        acca[3].x *= rh.w; acca[3].y *= rh.w; acca[3].z *= rh.w; acca[3].w *= rh.w;
    }

    #pragma unroll
    for (int oi = 0; oi < 4; ++oi) {
        float4 am = accm[oi], aa = acca[oi];
        float4 oc, os;
        float ex;
        ex = __expf(am.x); oc.x = ex * __cosf(aa.x); os.x = ex * __sinf(aa.x);
        ex = __expf(am.y); oc.y = ex * __cosf(aa.y); os.y = ex * __sinf(aa.y);
        ex = __expf(am.z); oc.z = ex * __cosf(aa.z); os.z = ex * __sinf(aa.z);
        ex = __expf(am.w); oc.w = ex * __cosf(aa.w); os.w = ex * __sinf(aa.w);
        size_t gi = ((size_t)(b * 2) * NC + o0 + oi) * NL + (size_t)iy * 64 + l0;
        *(float4*)&out[gi] = oc;
        *(float4*)&out[gi + (size_t)NC * NL] = os;
    }
}

extern "C" void kernel_launch(void* const* d_in, const int* in_sizes, int n_in,
                              void* d_out, int out_size, void* d_ws, size_t ws_size,
                              hipStream_t stream) {
    const float* x_mag = (const float*)d_in[0];
    const float* x_ang = (const float*)d_in[1];
    const float* w_mag = (const float*)d_in[2];
    const float* w_ang = (const float*)d_in[3];
    const float* w1    = (const float*)d_in[4];
    const float* w2    = (const float*)d_in[5];
    float* out = (float*)d_out;
    float* ws  = (float*)d_ws;

    prep_kernel<<<16, 256, 0, stream>>>(w_mag, w_ang, w1, w2, ws);
    fused_kernel<<<NB * 64, 256, 0, stream>>>(x_mag, x_ang, ws, out);
}